// Round 17
// baseline (183.625 us; speedup 1.0000x reference)
//
#include <hip/hip_runtime.h>
#include <hip/hip_bf16.h>
#include <math.h>

// ---------------------------------------------------------------------------
// KAN 2-layer forward, R17 = R10 pipeline (best known, 36.3us) + component-
// isolation probes for the conv_w mystery (coef1 consumers run at 0.8-2.2TB/s
// in every structured kernel; a grid-stride probe hits 5.6TB/s).
//   V4 x16: grid-stride load-only (control)
//   V3 x16: block-localized load-only (R13 conv_w addressing, sums)
//   V2 x16: V3 + LDS de-interleave + f2bf convert (no global store)
//   V1 x16: full conv_w incl. swizzled stores (to scratch Wg2)
// Deltas isolate {read-pattern, convert, store}.  Pipeline output unchanged.
// ---------------------------------------------------------------------------

#define B_DIM   128
#define IN1     3072
#define OUT1    256
#define NB      8
#define OUT2    10

#define KTOT    27648            // 9 * 3072
#define ROWB    55296            // KTOT * 2 bytes per row
#define SPLITK  108              // k-chunks (each 256 k = 4 stages of 64 k)
#define BN      64
#define PREP    16               // probe amplification

typedef short  bf16x8 __attribute__((ext_vector_type(8)));
typedef float  f32x4  __attribute__((ext_vector_type(4)));
typedef unsigned short ushort_t;
typedef unsigned int u32;

__device__ __forceinline__ ushort_t f2bf(float f) {
    union { __hip_bfloat16 h; ushort_t u; } v;
    v.h = __float2bfloat16(f);
    return v.u;
}
__device__ __forceinline__ float bf2f(ushort_t h) {
    union { float f; u32 u; } v; v.u = ((u32)h) << 16;
    return v.f;
}

__device__ __forceinline__ void gl_lds16(const void* g, void* l) {
    __builtin_amdgcn_global_load_lds(
        (const __attribute__((address_space(1))) u32*)g,
        (__attribute__((address_space(3))) u32*)l, 16, 0, 0);
}

// cardinal cubic B-spline basis (8 funcs) + silu, closed form (== Cox-de Boor
// recursion of the reference on the uniform extended grid [-2.2,2.2], h=0.4).
__device__ __forceinline__ void basis_silu(float x, float w[8], float& sil) {
    sil = x / (1.0f + __expf(-x));
    float u  = (x + 2.2f) * 2.5f;
    float uf = floorf(u);
    int   j  = (int)uf;
    float t  = u - uf;
    float omt = 1.0f - t;
    float t2 = t * t, t3 = t2 * t;
    float w0 = omt * omt * omt * (1.0f / 6.0f);
    float w1 = (3.0f * t3 - 6.0f * t2 + 4.0f) * (1.0f / 6.0f);
    float w2 = (-3.0f * t3 + 3.0f * t2 + 3.0f * t + 1.0f) * (1.0f / 6.0f);
    float w3 = t3 * (1.0f / 6.0f);
    bool valid = (u >= 0.0f) && (u < 11.0f);
#pragma unroll
    for (int g = 0; g < 8; ++g) {
        int m = g - j + 3;
        float v = (m == 0) ? w0 : (m == 1) ? w1 : (m == 2) ? w2 : (m == 3) ? w3 : 0.0f;
        w[g] = valid ? v : 0.0f;
    }
}

__device__ __forceinline__ float selu_f(float x) {
    const float scale = 1.0507009873554805f;
    const float alpha = 1.6732632423543772f;
    return (x > 0.0f) ? scale * x : scale * alpha * (__expf(x) - 1.0f);
}

// ===========================================================================
// R10 PIPELINE (verbatim)
// ===========================================================================
__global__ __launch_bounds__(128) void kconv(const float* __restrict__ x,
                                             const float* __restrict__ coef1,
                                             const float* __restrict__ sb1,
                                             const float* __restrict__ ssp1,
                                             char* __restrict__ Ag,
                                             char* __restrict__ Wg) {
    const int blk = blockIdx.x;
    if (blk < 384) {
        const int gid = blk * 128 + threadIdx.x;
        const int b  = gid / 384;
        const int ig = gid - b * 384;
        const int i0 = ig * 8;

        float4 x0 = *reinterpret_cast<const float4*>(x + (size_t)b * IN1 + i0);
        float4 x1 = *reinterpret_cast<const float4*>(x + (size_t)b * IN1 + i0 + 4);
        float xa[8] = {x0.x, x0.y, x0.z, x0.w, x1.x, x1.y, x1.z, x1.w};

        float bs[8][8], sil[8];
#pragma unroll
        for (int p = 0; p < 8; ++p) basis_silu(xa[p], bs[p], sil[p]);

        char* rowp = Ag + (size_t)b * ROWB;
        const int qsw = ((ig & 7) ^ (b & 7)) << 4;
#pragma unroll
        for (int s = 0; s < 9; ++s) {
            ushort_t v[8];
#pragma unroll
            for (int p = 0; p < 8; ++p)
                v[p] = f2bf((s < 8) ? bs[p][s] : sil[p]);
            *reinterpret_cast<uint4*>(rowp + (s * 48 + (ig >> 3)) * 128 + qsw) =
                *reinterpret_cast<const uint4*>(v);
        }
    } else {
        const int gid = (blk - 384) * 128 + threadIdx.x;
        const int o  = gid / 384;
        const int ig = gid - o * 384;
        const int i0 = ig * 8;

        float cf[8][8], sspv[8], sbv[8];
#pragma unroll
        for (int p = 0; p < 8; ++p) {
            const float* cp = coef1 + ((size_t)o * IN1 + i0 + p) * NB;
            float4 c0 = *reinterpret_cast<const float4*>(cp);
            float4 c1 = *reinterpret_cast<const float4*>(cp + 4);
            cf[p][0] = c0.x; cf[p][1] = c0.y; cf[p][2] = c0.z; cf[p][3] = c0.w;
            cf[p][4] = c1.x; cf[p][5] = c1.y; cf[p][6] = c1.z; cf[p][7] = c1.w;
        }
        {
            float4 s0 = *reinterpret_cast<const float4*>(ssp1 + (size_t)o * IN1 + i0);
            float4 s1 = *reinterpret_cast<const float4*>(ssp1 + (size_t)o * IN1 + i0 + 4);
            sspv[0]=s0.x; sspv[1]=s0.y; sspv[2]=s0.z; sspv[3]=s0.w;
            sspv[4]=s1.x; sspv[5]=s1.y; sspv[6]=s1.z; sspv[7]=s1.w;
            float4 b0 = *reinterpret_cast<const float4*>(sb1 + (size_t)o * IN1 + i0);
            float4 b1 = *reinterpret_cast<const float4*>(sb1 + (size_t)o * IN1 + i0 + 4);
            sbv[0]=b0.x; sbv[1]=b0.y; sbv[2]=b0.z; sbv[3]=b0.w;
            sbv[4]=b1.x; sbv[5]=b1.y; sbv[6]=b1.z; sbv[7]=b1.w;
        }

        char* rowp = Wg + (size_t)o * ROWB;
        const int qsw = ((ig & 7) ^ (o & 7)) << 4;
#pragma unroll
        for (int s = 0; s < 9; ++s) {
            ushort_t v[8];
#pragma unroll
            for (int p = 0; p < 8; ++p)
                v[p] = f2bf((s < 8) ? cf[p][s] * sspv[p] : sbv[p]);
            *reinterpret_cast<uint4*>(rowp + (s * 48 + (ig >> 3)) * 128 + qsw) =
                *reinterpret_cast<const uint4*>(v);
        }
    }
}

__global__ __launch_bounds__(512) void kgemm(const char* __restrict__ Ag,
                                             const char* __restrict__ Wg,
                                             ushort_t* __restrict__ partial) {
    __shared__ __align__(16) char lds[2][24576];

    const int tid = threadIdx.x;
    const int w   = tid >> 6, l = tid & 63;
    const int nt  = blockIdx.x, kc = blockIdx.y;
    const int o0  = nt * BN;

    const int ar0 = tid >> 3;
    const int ar1 = 64 + (tid >> 3);
    const int aq  = tid & 7;
    const char* Asrc0 = Ag + (size_t)ar0 * ROWB + ((aq ^ (ar0 & 7)) << 4);
    const char* Asrc1 = Ag + (size_t)ar1 * ROWB + ((aq ^ (ar1 & 7)) << 4);
    const int wr = tid >> 3;
    const char* Wsrc = Wg + (size_t)(o0 + wr) * ROWB + ((aq ^ (wr & 7)) << 4);

#define ISSUE(ss, buf)                                                        \
    {                                                                         \
        const int cb = (kc * 4 + (ss)) * 128;                                 \
        char* base = &lds[buf][0];                                            \
        gl_lds16(Asrc0 + cb, base + w * 1024);                                \
        gl_lds16(Asrc1 + cb, base + 8192 + w * 1024);                         \
        gl_lds16(Wsrc  + cb, base + 16384 + w * 1024);                        \
    }

    f32x4 acc[2][2];
#pragma unroll
    for (int a = 0; a < 2; ++a)
#pragma unroll
        for (int bq = 0; bq < 2; ++bq) acc[a][bq] = (f32x4){0.f, 0.f, 0.f, 0.f};

    const int mq = w >> 1, nq = w & 1;
    const int r16 = l & 15, k16 = l >> 4;

    ISSUE(0, 0)
    ISSUE(1, 1)

#pragma unroll
    for (int s = 0; s < 4; ++s) {
        if (s < 3) { asm volatile("s_waitcnt vmcnt(3)" ::: "memory"); }
        else       { asm volatile("s_waitcnt vmcnt(0)" ::: "memory"); }
        __builtin_amdgcn_s_barrier();
        asm volatile("" ::: "memory");

        const char* Ab = &lds[s & 1][0];
        const char* Wb = &lds[s & 1][16384];
#pragma unroll
        for (int ks = 0; ks < 2; ++ks) {
            const int qf = ks * 4 + k16;
            bf16x8 bf[2], af[2];
#pragma unroll
            for (int bq = 0; bq < 2; ++bq) {
                const int rn = nq * 32 + bq * 16 + r16;
                bf[bq] = *reinterpret_cast<const bf16x8*>(Wb + rn * 128 + ((qf ^ (rn & 7)) << 4));
            }
#pragma unroll
            for (int a = 0; a < 2; ++a) {
                const int rm = mq * 32 + a * 16 + r16;
                af[a] = *reinterpret_cast<const bf16x8*>(Ab + rm * 128 + ((qf ^ (rm & 7)) << 4));
            }
#pragma unroll
            for (int a = 0; a < 2; ++a)
#pragma unroll
                for (int bq = 0; bq < 2; ++bq)
                    acc[a][bq] = __builtin_amdgcn_mfma_f32_16x16x32_bf16(af[a], bf[bq], acc[a][bq], 0, 0, 0);
        }

        __builtin_amdgcn_s_barrier();
        asm volatile("" ::: "memory");
        if (s == 0) ISSUE(2, 0)
        if (s == 1) ISSUE(3, 1)
    }
#undef ISSUE

    ushort_t* pp = partial + (size_t)kc * (B_DIM * OUT1);
#pragma unroll
    for (int a = 0; a < 2; ++a) {
#pragma unroll
        for (int bq = 0; bq < 2; ++bq) {
            const int col = o0 + nq * 32 + bq * 16 + r16;
#pragma unroll
            for (int r = 0; r < 4; ++r) {
                const int row = mq * 32 + a * 16 + k16 * 4 + r;
                pp[(size_t)row * OUT1 + col] = f2bf(acc[a][bq][r]);
            }
        }
    }
}

#define CPG (SPLITK / 4)   // 27
__global__ __launch_bounds__(256) void klayer2r(const ushort_t* __restrict__ partial,
                                                const float* __restrict__ coef2,
                                                const float* __restrict__ sb2,
                                                const float* __restrict__ ssp2,
                                                float* __restrict__ out) {
    const int b = blockIdx.x;
    const int t = threadIdx.x;
    const int w = t >> 6, l = t & 63;

    f32x4 s = {0.f, 0.f, 0.f, 0.f};
    const ushort_t* pb = partial + (size_t)b * OUT1 + l * 4;
#pragma unroll
    for (int c = 0; c < 27; ++c) {
        ushort4 v = *reinterpret_cast<const ushort4*>(
            pb + (size_t)(w + 4 * c) * (B_DIM * OUT1));
        s[0] += bf2f(v.x); s[1] += bf2f(v.y); s[2] += bf2f(v.z); s[3] += bf2f(v.w);
    }

    __shared__ float sums[4][OUT1];
    *reinterpret_cast<float4*>(&sums[w][l * 4]) = (float4){s[0], s[1], s[2], s[3]};
    __syncthreads();

    const float hv = sums[0][t] + sums[1][t] + sums[2][t] + sums[3][t];
    const float sh = selu_f(hv);
    float w8[8], sil;
    basis_silu(sh, w8, sil);

    float accs[OUT2];
#pragma unroll
    for (int oo = 0; oo < OUT2; ++oo) {
        const float* cp = coef2 + ((size_t)oo * OUT1 + t) * NB;
        float4 c0 = *reinterpret_cast<const float4*>(cp);
        float4 c1 = *reinterpret_cast<const float4*>(cp + 4);
        float dot = w8[0] * c0.x + w8[1] * c0.y + w8[2] * c0.z + w8[3] * c0.w +
                    w8[4] * c1.x + w8[5] * c1.y + w8[6] * c1.z + w8[7] * c1.w;
        accs[oo] = sb2[oo * OUT1 + t] * sil + ssp2[oo * OUT1 + t] * dot;
    }

    __shared__ float red[4][OUT2];
#pragma unroll
    for (int oo = 0; oo < OUT2; ++oo) {
        float v = accs[oo];
#pragma unroll
        for (int off = 32; off >= 1; off >>= 1) v += __shfl_xor(v, off, 64);
        if (l == 0) red[w][oo] = v;
    }
    __syncthreads();
    if (t < OUT2)
        out[b * OUT2 + t] = red[0][t] + red[1][t] + red[2][t] + red[3][t];
}

// ===========================================================================
// PROBES (x16 each, read coef1/ssp1/sb1, write far scratch only)
// ===========================================================================
// V4: grid-stride load-only control.  1024 blocks x 256 thr.
__global__ __launch_bounds__(256) void kprobe_v4(const float4* __restrict__ src,
                                                 float* __restrict__ dst) {
    const size_t tid = (size_t)blockIdx.x * 256 + threadIdx.x;
    float acc = 0.0f;
#pragma unroll 1
    for (int rep = 0; rep < PREP; ++rep) {
        asm volatile("" ::: "memory");
#pragma unroll
        for (int j = 0; j < 6; ++j) {
            float4 v = src[tid + (size_t)j * 262144];
            acc += v.x + v.y + v.z + v.w;
        }
    }
    dst[tid] = acc;
}

// V3: block-localized load-only (R13 conv_w addressing).  768 blocks x 256.
__global__ __launch_bounds__(256) void kprobe_v3(const float* __restrict__ coef1,
                                                 const float* __restrict__ sb1,
                                                 const float* __restrict__ ssp1,
                                                 float* __restrict__ dst) {
    const int tid = threadIdx.x;
    const int o  = blockIdx.x / 3;
    const int i0 = (blockIdx.x % 3) * 1024;
    float acc = 0.0f;
#pragma unroll 1
    for (int rep = 0; rep < PREP; ++rep) {
        asm volatile("" ::: "memory");
        const float* cbase = coef1 + ((size_t)o * IN1 + i0) * NB;
        float4 s = {0.f, 0.f, 0.f, 0.f};
#pragma unroll
        for (int j = 0; j < 8; ++j) {
            float4 c = *reinterpret_cast<const float4*>(cbase + j * 1024 + tid * 4);
            s.x += c.x; s.y += c.y; s.z += c.z; s.w += c.w;
        }
        float4 sv = *reinterpret_cast<const float4*>(ssp1 + (size_t)o * IN1 + i0 + tid * 4);
        float4 bv = *reinterpret_cast<const float4*>(sb1 + (size_t)o * IN1 + i0 + tid * 4);
        acc += s.x + s.y + s.z + s.w + sv.x + sv.y + sv.z + sv.w +
               bv.x + bv.y + bv.z + bv.w;
    }
    dst[blockIdx.x * 256 + tid] = acc;
}

// V2: V3 + LDS de-interleave + f2bf convert, no global store.  768 x 256.
#define WROWD 1032
__global__ __launch_bounds__(256) void kprobe_v2(const float* __restrict__ coef1,
                                                 const float* __restrict__ sb1,
                                                 const float* __restrict__ ssp1,
                                                 u32* __restrict__ dst) {
    __shared__ float cb[8][WROWD];
    __shared__ float sspl[1024];
    __shared__ float sbl[1024];
    const int tid = threadIdx.x;
    const int o  = blockIdx.x / 3;
    const int i0 = (blockIdx.x % 3) * 1024;
    u32 keep = 0;
#pragma unroll 1
    for (int rep = 0; rep < PREP; ++rep) {
        asm volatile("" ::: "memory");
        {
            const float* cbase = coef1 + ((size_t)o * IN1 + i0) * NB;
            const int s0 = (tid & 1) * 4;
            const int ih = tid >> 1;
#pragma unroll
            for (int j = 0; j < 8; ++j) {
                float4 c = *reinterpret_cast<const float4*>(cbase + j * 1024 + tid * 4);
                const int iloc = j * 128 + ih;
                cb[s0 + 0][iloc] = c.x;
                cb[s0 + 1][iloc] = c.y;
                cb[s0 + 2][iloc] = c.z;
                cb[s0 + 3][iloc] = c.w;
            }
            *reinterpret_cast<float4*>(&sspl[tid * 4]) =
                *reinterpret_cast<const float4*>(ssp1 + (size_t)o * IN1 + i0 + tid * 4);
            *reinterpret_cast<float4*>(&sbl[tid * 4]) =
                *reinterpret_cast<const float4*>(sb1 + (size_t)o * IN1 + i0 + tid * 4);
        }
        __syncthreads();
#pragma unroll
        for (int r = 0; r < 5; ++r) {
            const int u = tid + r * 256;
            if (u < 1152) {
                const int s = u >> 7, q = u & 127;
                ushort_t v[8];
                if (s < 8) {
                    float4 ca = *reinterpret_cast<const float4*>(&cb[s][q * 8]);
                    float4 cc = *reinterpret_cast<const float4*>(&cb[s][q * 8 + 4]);
                    float4 sa = *reinterpret_cast<const float4*>(&sspl[q * 8]);
                    float4 sc = *reinterpret_cast<const float4*>(&sspl[q * 8 + 4]);
                    v[0] = f2bf(ca.x * sa.x); v[1] = f2bf(ca.y * sa.y);
                    v[2] = f2bf(ca.z * sa.z); v[3] = f2bf(ca.w * sa.w);
                    v[4] = f2bf(cc.x * sc.x); v[5] = f2bf(cc.y * sc.y);
                    v[6] = f2bf(cc.z * sc.z); v[7] = f2bf(cc.w * sc.w);
                } else {
                    float4 ba = *reinterpret_cast<const float4*>(&sbl[q * 8]);
                    float4 bc = *reinterpret_cast<const float4*>(&sbl[q * 8 + 4]);
                    v[0] = f2bf(ba.x); v[1] = f2bf(ba.y); v[2] = f2bf(ba.z); v[3] = f2bf(ba.w);
                    v[4] = f2bf(bc.x); v[5] = f2bf(bc.y); v[6] = f2bf(bc.z); v[7] = f2bf(bc.w);
                }
                const uint4* vv = reinterpret_cast<const uint4*>(v);
                keep ^= vv->x ^ vv->y ^ vv->z ^ vv->w;
            }
        }
        __syncthreads();
    }
    dst[blockIdx.x * 256 + tid] = keep;
}

// V1: full conv_w x16 -> scratch Wg2.  768 x 256.
__global__ __launch_bounds__(256) void kprobe_v1(const float* __restrict__ coef1,
                                                 const float* __restrict__ sb1,
                                                 const float* __restrict__ ssp1,
                                                 char* __restrict__ Wg2) {
    __shared__ float cb[8][WROWD];
    __shared__ float sspl[1024];
    __shared__ float sbl[1024];
    const int tid = threadIdx.x;
    const int o  = blockIdx.x / 3;
    const int i0 = (blockIdx.x % 3) * 1024;
#pragma unroll 1
    for (int rep = 0; rep < PREP; ++rep) {
        asm volatile("" ::: "memory");
        {
            const float* cbase = coef1 + ((size_t)o * IN1 + i0) * NB;
            const int s0 = (tid & 1) * 4;
            const int ih = tid >> 1;
#pragma unroll
            for (int j = 0; j < 8; ++j) {
                float4 c = *reinterpret_cast<const float4*>(cbase + j * 1024 + tid * 4);
                const int iloc = j * 128 + ih;
                cb[s0 + 0][iloc] = c.x;
                cb[s0 + 1][iloc] = c.y;
                cb[s0 + 2][iloc] = c.z;
                cb[s0 + 3][iloc] = c.w;
            }
            *reinterpret_cast<float4*>(&sspl[tid * 4]) =
                *reinterpret_cast<const float4*>(ssp1 + (size_t)o * IN1 + i0 + tid * 4);
            *reinterpret_cast<float4*>(&sbl[tid * 4]) =
                *reinterpret_cast<const float4*>(sb1 + (size_t)o * IN1 + i0 + tid * 4);
        }
        __syncthreads();
        char* rowp = Wg2 + (size_t)o * ROWB;
        const int osw = o & 7;
#pragma unroll
        for (int r = 0; r < 5; ++r) {
            const int u = tid + r * 256;
            if (u < 1152) {
                const int s = u >> 7, q = u & 127;
                const int ig = (i0 >> 3) + q;
                ushort_t v[8];
                if (s < 8) {
                    float4 ca = *reinterpret_cast<const float4*>(&cb[s][q * 8]);
                    float4 cc = *reinterpret_cast<const float4*>(&cb[s][q * 8 + 4]);
                    float4 sa = *reinterpret_cast<const float4*>(&sspl[q * 8]);
                    float4 sc = *reinterpret_cast<const float4*>(&sspl[q * 8 + 4]);
                    v[0] = f2bf(ca.x * sa.x); v[1] = f2bf(ca.y * sa.y);
                    v[2] = f2bf(ca.z * sa.z); v[3] = f2bf(ca.w * sa.w);
                    v[4] = f2bf(cc.x * sc.x); v[5] = f2bf(cc.y * sc.y);
                    v[6] = f2bf(cc.z * sc.z); v[7] = f2bf(cc.w * sc.w);
                } else {
                    float4 ba = *reinterpret_cast<const float4*>(&sbl[q * 8]);
                    float4 bc = *reinterpret_cast<const float4*>(&sbl[q * 8 + 4]);
                    v[0] = f2bf(ba.x); v[1] = f2bf(ba.y); v[2] = f2bf(ba.z); v[3] = f2bf(ba.w);
                    v[4] = f2bf(bc.x); v[5] = f2bf(bc.y); v[6] = f2bf(bc.z); v[7] = f2bf(bc.w);
                }
                *reinterpret_cast<uint4*>(rowp + (s * 48 + (ig >> 3)) * 128 +
                                          (((ig & 7) ^ osw) << 4)) =
                    *reinterpret_cast<const uint4*>(v);
            }
        }
        __syncthreads();
    }
}

// ---------------------------------------------------------------------------
extern "C" void kernel_launch(void* const* d_in, const int* in_sizes, int n_in,
                              void* d_out, int out_size, void* d_ws, size_t ws_size,
                              hipStream_t stream) {
    const float* x     = (const float*)d_in[0];
    const float* coef1 = (const float*)d_in[1];
    const float* sb1   = (const float*)d_in[2];
    const float* ssp1  = (const float*)d_in[3];
    const float* coef2 = (const float*)d_in[4];
    const float* sb2   = (const float*)d_in[5];
    const float* ssp2  = (const float*)d_in[6];
    float* out = (float*)d_out;

    char*     Ag      = (char*)d_ws;                             // 7,077,888 B
    char*     Wg      = Ag + (size_t)B_DIM * ROWB;               // 14,155,776 B
    ushort_t* partial = (ushort_t*)(Wg + (size_t)OUT1 * ROWB);   // 7,077,888 B
    float*    dstV4   = (float*)((char*)d_ws + (32u << 20));
    float*    dstV3   = (float*)((char*)d_ws + (34u << 20));
    u32*      dstV2   = (u32*)((char*)d_ws + (36u << 20));
    char*     Wg2     = (char*)d_ws + (40u << 20);               // 14.2 MB

    kconv<<<1152, 128, 0, stream>>>(x, coef1, sb1, ssp1, Ag, Wg);
    kgemm<<<dim3(OUT1 / BN, SPLITK), 512, 0, stream>>>(Ag, Wg, partial);
    klayer2r<<<B_DIM, 256, 0, stream>>>(partial, coef2, sb2, ssp2, out);

    kprobe_v4<<<1024, 256, 0, stream>>>((const float4*)coef1, dstV4);
    kprobe_v3<<<768, 256, 0, stream>>>(coef1, sb1, ssp1, dstV3);
    kprobe_v2<<<768, 256, 0, stream>>>(coef1, sb1, ssp1, dstV2);
    kprobe_v1<<<768, 256, 0, stream>>>(coef1, sb1, ssp1, Wg2);
}

// Round 18
// 166.423 us; speedup vs baseline: 1.1034x; 1.1034x over previous
//
#include <hip/hip_runtime.h>
#include <hip/hip_bf16.h>
#include <math.h>

// ---------------------------------------------------------------------------
// KAN 2-layer forward, R18: TWO dispatches.
//   D1 kconv_all: blocks 0..383 conv_a (R12 geometry), 384..1151 conv_w
//      (R13 two-phase — the exact code kprobe_v1 measured at ~5us/rep).
//      Block 0 also resets the completion counter for D2.
//   D2 kgemm_tail: R10 kgemm verbatim (432 blocks x 512); after the partial
//      stores each block threadfence+atomicAdd(done); blocks 0..127 poll
//      done==432 (1 lane, s_sleep) then run the 8-wave reduce+selu+layer2
//      for b = bid.  Coherence pattern (fence+release add / acquire poll)
//      validated by R15's P2->P3.
// ---------------------------------------------------------------------------

#define B_DIM   128
#define IN1     3072
#define OUT1    256
#define NB      8
#define OUT2    10

#define KTOT    27648            // 9 * 3072
#define ROWB    55296            // KTOT * 2 bytes per row
#define SPLITK  108              // k-chunks (each 256 k = 4 stages of 64 k)
#define BN      64
#define NBLK2   432              // 4 n-tiles x 108 k-chunks

typedef short  bf16x8 __attribute__((ext_vector_type(8)));
typedef float  f32x4  __attribute__((ext_vector_type(4)));
typedef unsigned short ushort_t;
typedef unsigned int u32;

__device__ __forceinline__ ushort_t f2bf(float f) {
    union { __hip_bfloat16 h; ushort_t u; } v;
    v.h = __float2bfloat16(f);
    return v.u;
}
__device__ __forceinline__ float bf2f(ushort_t h) {
    union { float f; u32 u; } v; v.u = ((u32)h) << 16;
    return v.f;
}

__device__ __forceinline__ void gl_lds16(const void* g, void* l) {
    __builtin_amdgcn_global_load_lds(
        (const __attribute__((address_space(1))) u32*)g,
        (__attribute__((address_space(3))) u32*)l, 16, 0, 0);
}

// cardinal cubic B-spline basis (8 funcs) + silu, closed form (== Cox-de Boor
// recursion of the reference on the uniform extended grid [-2.2,2.2], h=0.4).
__device__ __forceinline__ void basis_silu(float x, float w[8], float& sil) {
    sil = x / (1.0f + __expf(-x));
    float u  = (x + 2.2f) * 2.5f;
    float uf = floorf(u);
    int   j  = (int)uf;
    float t  = u - uf;
    float omt = 1.0f - t;
    float t2 = t * t, t3 = t2 * t;
    float w0 = omt * omt * omt * (1.0f / 6.0f);
    float w1 = (3.0f * t3 - 6.0f * t2 + 4.0f) * (1.0f / 6.0f);
    float w2 = (-3.0f * t3 + 3.0f * t2 + 3.0f * t + 1.0f) * (1.0f / 6.0f);
    float w3 = t3 * (1.0f / 6.0f);
    bool valid = (u >= 0.0f) && (u < 11.0f);
#pragma unroll
    for (int g = 0; g < 8; ++g) {
        int m = g - j + 3;
        float v = (m == 0) ? w0 : (m == 1) ? w1 : (m == 2) ? w2 : (m == 3) ? w3 : 0.0f;
        w[g] = valid ? v : 0.0f;
    }
}

__device__ __forceinline__ float selu_f(float x) {
    const float scale = 1.0507009873554805f;
    const float alpha = 1.6732632423543772f;
    return (x > 0.0f) ? scale * x : scale * alpha * (__expf(x) - 1.0f);
}

// ---------------------------------------------------------------------------
// D1: kconv_all.  1152 blocks x 256 thr.
// ---------------------------------------------------------------------------
__global__ __launch_bounds__(256) void kconv_all(const float* __restrict__ x,
                                                 const float* __restrict__ coef1,
                                                 const float* __restrict__ sb1,
                                                 const float* __restrict__ ssp1,
                                                 char* __restrict__ Ag,
                                                 char* __restrict__ Wg,
                                                 int* __restrict__ done) {
    __shared__ __align__(16) char smem[41216];
    const int tid = threadIdx.x;
    const int bid = blockIdx.x;

    if (bid == 0 && tid == 0)
        __hip_atomic_store(done, 0, __ATOMIC_RELAXED, __HIP_MEMORY_SCOPE_AGENT);

    if (bid < 384) {
        // ---- conv_a (R12 geometry): block (b = bid/3, i0 = (bid%3)*1024) ----
        ushort_t (*lA)[1032] = reinterpret_cast<ushort_t(*)[1032]>(smem);
        const int b  = bid / 3;
        const int i0 = (bid % 3) * 1024;
        {
            const int li = tid * 4;
            float4 xv = *reinterpret_cast<const float4*>(x + (size_t)b * IN1 + i0 + li);
            float xa[4] = {xv.x, xv.y, xv.z, xv.w};
#pragma unroll
            for (int p = 0; p < 4; ++p) {
                float bs[8], sil;
                basis_silu(xa[p], bs, sil);
#pragma unroll
                for (int s = 0; s < 8; ++s) lA[s][li + p] = f2bf(bs[s]);
                lA[8][li + p] = f2bf(sil);
            }
        }
        __syncthreads();
        char* rowp = Ag + (size_t)b * ROWB;
        const int bsw = b & 7;
#pragma unroll
        for (int r = 0; r < 5; ++r) {
            const int u = tid + r * 256;
            if (u < 1152) {
                const int s = u >> 7, q = u & 127;
                const int ig = (i0 >> 3) + q;
                uint4 v = *reinterpret_cast<const uint4*>(&lA[s][q * 8]);
                *reinterpret_cast<uint4*>(rowp + (s * 48 + (ig >> 3)) * 128 +
                                          (((ig & 7) ^ bsw) << 4)) = v;
            }
        }
    } else {
        // ---- conv_w (R13 two-phase): block (o = wb/3, i0 = (wb%3)*1024) ----
        float (*cb)[1032] = reinterpret_cast<float(*)[1032]>(smem);   // 33024 B
        float* sspl = reinterpret_cast<float*>(smem + 33024);         // 4096 B
        float* sbl  = reinterpret_cast<float*>(smem + 37120);         // 4096 B
        const int wb = bid - 384;
        const int o  = wb / 3;
        const int i0 = (wb % 3) * 1024;

        {
            const float* cbase = coef1 + ((size_t)o * IN1 + i0) * NB;
            const int s0 = (tid & 1) * 4;
            const int ih = tid >> 1;
#pragma unroll
            for (int j = 0; j < 8; ++j) {
                float4 c = *reinterpret_cast<const float4*>(cbase + j * 1024 + tid * 4);
                const int iloc = j * 128 + ih;
                cb[s0 + 0][iloc] = c.x;
                cb[s0 + 1][iloc] = c.y;
                cb[s0 + 2][iloc] = c.z;
                cb[s0 + 3][iloc] = c.w;
            }
            *reinterpret_cast<float4*>(&sspl[tid * 4]) =
                *reinterpret_cast<const float4*>(ssp1 + (size_t)o * IN1 + i0 + tid * 4);
            *reinterpret_cast<float4*>(&sbl[tid * 4]) =
                *reinterpret_cast<const float4*>(sb1 + (size_t)o * IN1 + i0 + tid * 4);
        }
        __syncthreads();

        char* rowp = Wg + (size_t)o * ROWB;
        const int osw = o & 7;
#pragma unroll
        for (int r = 0; r < 5; ++r) {
            const int u = tid + r * 256;
            if (u < 1152) {
                const int s = u >> 7, q = u & 127;
                const int ig = (i0 >> 3) + q;
                ushort_t v[8];
                if (s < 8) {
                    float4 ca = *reinterpret_cast<const float4*>(&cb[s][q * 8]);
                    float4 cc = *reinterpret_cast<const float4*>(&cb[s][q * 8 + 4]);
                    float4 sa = *reinterpret_cast<const float4*>(&sspl[q * 8]);
                    float4 sc = *reinterpret_cast<const float4*>(&sspl[q * 8 + 4]);
                    v[0] = f2bf(ca.x * sa.x); v[1] = f2bf(ca.y * sa.y);
                    v[2] = f2bf(ca.z * sa.z); v[3] = f2bf(ca.w * sa.w);
                    v[4] = f2bf(cc.x * sc.x); v[5] = f2bf(cc.y * sc.y);
                    v[6] = f2bf(cc.z * sc.z); v[7] = f2bf(cc.w * sc.w);
                } else {
                    float4 ba = *reinterpret_cast<const float4*>(&sbl[q * 8]);
                    float4 bc = *reinterpret_cast<const float4*>(&sbl[q * 8 + 4]);
                    v[0] = f2bf(ba.x); v[1] = f2bf(ba.y); v[2] = f2bf(ba.z); v[3] = f2bf(ba.w);
                    v[4] = f2bf(bc.x); v[5] = f2bf(bc.y); v[6] = f2bf(bc.z); v[7] = f2bf(bc.w);
                }
                *reinterpret_cast<uint4*>(rowp + (s * 48 + (ig >> 3)) * 128 +
                                          (((ig & 7) ^ osw) << 4)) =
                    *reinterpret_cast<const uint4*>(v);
            }
        }
    }
}

// ---------------------------------------------------------------------------
// D2: kgemm_tail.  432 blocks x 512 thr.  R10 kgemm + counter-gated reduce.
// ---------------------------------------------------------------------------
__global__ __launch_bounds__(512, 4) void kgemm_tail(
        const char* __restrict__ Ag,
        const char* __restrict__ Wg,
        ushort_t* __restrict__ partial,
        const float* __restrict__ coef2,
        const float* __restrict__ sb2,
        const float* __restrict__ ssp2,
        float* __restrict__ out,
        int* __restrict__ done) {
    __shared__ __align__(16) char smem[49152];   // gemm: 2 bufs x 24576

    const int tid = threadIdx.x;
    const int bid = blockIdx.x;
    const int w   = tid >> 6, l = tid & 63;
    const int nt  = bid & 3, kc = bid >> 2;
    const int o0  = nt * BN;

    // ================= GEMM phase (R10 verbatim) =================
    {
        char* L0 = smem;
        char* L1 = smem + 24576;

        const int ar0 = tid >> 3;
        const int ar1 = 64 + (tid >> 3);
        const int aq  = tid & 7;
        const char* Asrc0 = Ag + (size_t)ar0 * ROWB + ((aq ^ (ar0 & 7)) << 4);
        const char* Asrc1 = Ag + (size_t)ar1 * ROWB + ((aq ^ (ar1 & 7)) << 4);
        const int wr = tid >> 3;
        const char* Wsrc = Wg + (size_t)(o0 + wr) * ROWB + ((aq ^ (wr & 7)) << 4);

#define ISSUE(ss, base)                                                       \
        {                                                                     \
            const int cb_ = (kc * 4 + (ss)) * 128;                            \
            gl_lds16(Asrc0 + cb_, (base) + w * 1024);                         \
            gl_lds16(Asrc1 + cb_, (base) + 8192 + w * 1024);                  \
            gl_lds16(Wsrc  + cb_, (base) + 16384 + w * 1024);                 \
        }

        f32x4 acc[2][2];
#pragma unroll
        for (int a = 0; a < 2; ++a)
#pragma unroll
            for (int bq = 0; bq < 2; ++bq) acc[a][bq] = (f32x4){0.f, 0.f, 0.f, 0.f};

        const int mq = w >> 1, nq = w & 1;
        const int r16 = l & 15, k16 = l >> 4;

        ISSUE(0, L0)
        ISSUE(1, L1)

#pragma unroll
        for (int s = 0; s < 4; ++s) {
            if (s < 3) { asm volatile("s_waitcnt vmcnt(3)" ::: "memory"); }
            else       { asm volatile("s_waitcnt vmcnt(0)" ::: "memory"); }
            __builtin_amdgcn_s_barrier();
            asm volatile("" ::: "memory");

            const char* Ab = (s & 1) ? L1 : L0;
            const char* Wb = ((s & 1) ? L1 : L0) + 16384;
#pragma unroll
            for (int ks = 0; ks < 2; ++ks) {
                const int qf = ks * 4 + k16;
                bf16x8 bf[2], af[2];
#pragma unroll
                for (int bq = 0; bq < 2; ++bq) {
                    const int rn = nq * 32 + bq * 16 + r16;
                    bf[bq] = *reinterpret_cast<const bf16x8*>(Wb + rn * 128 + ((qf ^ (rn & 7)) << 4));
                }
#pragma unroll
                for (int a = 0; a < 2; ++a) {
                    const int rm = mq * 32 + a * 16 + r16;
                    af[a] = *reinterpret_cast<const bf16x8*>(Ab + rm * 128 + ((qf ^ (rm & 7)) << 4));
                }
#pragma unroll
                for (int a = 0; a < 2; ++a)
#pragma unroll
                    for (int bq = 0; bq < 2; ++bq)
                        acc[a][bq] = __builtin_amdgcn_mfma_f32_16x16x32_bf16(af[a], bf[bq], acc[a][bq], 0, 0, 0);
            }

            __builtin_amdgcn_s_barrier();
            asm volatile("" ::: "memory");
            if (s == 0) ISSUE(2, L0)
            if (s == 1) ISSUE(3, L1)
        }
#undef ISSUE

        ushort_t* pp = partial + (size_t)kc * (B_DIM * OUT1);
#pragma unroll
        for (int a = 0; a < 2; ++a) {
#pragma unroll
            for (int bq = 0; bq < 2; ++bq) {
                const int col = o0 + nq * 32 + bq * 16 + r16;
#pragma unroll
                for (int r = 0; r < 4; ++r) {
                    const int row = mq * 32 + a * 16 + k16 * 4 + r;
                    pp[(size_t)row * OUT1 + col] = f2bf(acc[a][bq][r]);
                }
            }
        }
    }

    // ================= completion signal =================
    __threadfence();                // release my partial stores device-wide
    __syncthreads();                // all waves of this block done storing
    if (tid == 0)
        __hip_atomic_fetch_add(done, 1, __ATOMIC_ACQ_REL, __HIP_MEMORY_SCOPE_AGENT);

    if (bid >= B_DIM) return;

    // ================= reduce + selu + layer2 (blocks 0..127) =================
    if (tid == 0) {
        while (__hip_atomic_load(done, __ATOMIC_ACQUIRE, __HIP_MEMORY_SCOPE_AGENT) < NBLK2)
            __builtin_amdgcn_s_sleep(8);
    }
    __syncthreads();
    __threadfence();

    {
        const int b = bid;
        float (*sums)[OUT1] = reinterpret_cast<float(*)[OUT1]>(smem);   // 8x256 f32
        float (*red)[OUT2]  = reinterpret_cast<float(*)[OUT2]>(smem + 8192);

        f32x4 s = {0.f, 0.f, 0.f, 0.f};
        const ushort_t* pb = partial + (size_t)b * OUT1 + l * 4;
#pragma unroll
        for (int c = 0; c < 13; ++c) {
            ushort4 v = *reinterpret_cast<const ushort4*>(
                pb + (size_t)(w + 8 * c) * (B_DIM * OUT1));
            s[0] += bf2f(v.x); s[1] += bf2f(v.y); s[2] += bf2f(v.z); s[3] += bf2f(v.w);
        }
        if (w < 4) {
            ushort4 v = *reinterpret_cast<const ushort4*>(
                pb + (size_t)(w + 104) * (B_DIM * OUT1));
            s[0] += bf2f(v.x); s[1] += bf2f(v.y); s[2] += bf2f(v.z); s[3] += bf2f(v.w);
        }
        *reinterpret_cast<float4*>(&sums[w][l * 4]) = (float4){s[0], s[1], s[2], s[3]};
        __syncthreads();

        if (tid < OUT1) {
            float hv = 0.0f;
#pragma unroll
            for (int ww = 0; ww < 8; ++ww) hv += sums[ww][tid];
            const float sh = selu_f(hv);
            float w8[8], sil;
            basis_silu(sh, w8, sil);

            float accs[OUT2];
#pragma unroll
            for (int oo = 0; oo < OUT2; ++oo) {
                const float* cp = coef2 + ((size_t)oo * OUT1 + tid) * NB;
                float4 c0 = *reinterpret_cast<const float4*>(cp);
                float4 c1 = *reinterpret_cast<const float4*>(cp + 4);
                float dot = w8[0] * c0.x + w8[1] * c0.y + w8[2] * c0.z + w8[3] * c0.w +
                            w8[4] * c1.x + w8[5] * c1.y + w8[6] * c1.z + w8[7] * c1.w;
                accs[oo] = sb2[oo * OUT1 + tid] * sil + ssp2[oo * OUT1 + tid] * dot;
            }

#pragma unroll
            for (int oo = 0; oo < OUT2; ++oo) {
                float v = accs[oo];
#pragma unroll
                for (int off = 32; off >= 1; off >>= 1) v += __shfl_xor(v, off, 64);
                if (l == 0) red[w][oo] = v;
            }
        }
        __syncthreads();
        if (tid < OUT2)
            out[b * OUT2 + tid] = red[0][tid] + red[1][tid] + red[2][tid] + red[3][tid];
    }
}

// ---------------------------------------------------------------------------
extern "C" void kernel_launch(void* const* d_in, const int* in_sizes, int n_in,
                              void* d_out, int out_size, void* d_ws, size_t ws_size,
                              hipStream_t stream) {
    const float* x     = (const float*)d_in[0];
    const float* coef1 = (const float*)d_in[1];
    const float* sb1   = (const float*)d_in[2];
    const float* ssp1  = (const float*)d_in[3];
    const float* coef2 = (const float*)d_in[4];
    const float* sb2   = (const float*)d_in[5];
    const float* ssp2  = (const float*)d_in[6];
    float* out = (float*)d_out;

    char*     Ag      = (char*)d_ws;                             // 7,077,888 B
    char*     Wg      = Ag + (size_t)B_DIM * ROWB;               // 14,155,776 B
    ushort_t* partial = (ushort_t*)(Wg + (size_t)OUT1 * ROWB);   // 7,077,888 B
    int*      done    = (int*)((char*)d_ws + 28311552);          // 4 B

    kconv_all<<<1152, 256, 0, stream>>>(x, coef1, sb1, ssp1, Ag, Wg, done);
    kgemm_tail<<<NBLK2, 512, 0, stream>>>(Ag, Wg, partial, coef2, sb2, ssp2, out, done);
}